// Round 4
// baseline (1499.270 us; speedup 1.0000x reference)
//
#include <hip/hip_runtime.h>
#include <math.h>

#define D_DIM 1024
#define M_DIM 256
#define B_IMG 64
#define N_TOK 512
#define BN    32768

typedef unsigned short u16;
typedef __attribute__((ext_vector_type(8))) __bf16 bf16x8;
typedef __attribute__((ext_vector_type(4))) float  f32x4;

__device__ __forceinline__ u16 f2bf(float f) {
  union { float f; unsigned u; } c; c.f = f;
  unsigned u = c.u;
  return (u16)((u + 0x7FFFu + ((u >> 16) & 1u)) >> 16);
}
__device__ __forceinline__ float bf2f(u16 h) {
  union { unsigned u; float f; } c; c.u = ((unsigned)h) << 16;
  return c.f;
}

// ---------------------------------------------------------------------------
// Input-dtype detector. flag: 0 = inputs are bf16, 1 = inputs are f32.
// Even-index u16s of bf16 N(0,1) data are all sane bf16; of f32 data they are
// mantissa-low garbage (~30% sane each; P(all 64 sane) ~ 1e-33).
// ---------------------------------------------------------------------------
__global__ __launch_bounds__(64) void detect_dtype(const u16* __restrict__ p, int* __restrict__ dflag)
{
  const int lane = threadIdx.x;
  const float a = fabsf(bf2f(p[lane * 2]));
  const bool sane = (a >= 1e-20f && a <= 1e3f);
  const unsigned long long m = __ballot(sane);
  if (lane == 0) *dflag = (m == ~0ull) ? 0 : 1;
}

__device__ __forceinline__ float load_in(const void* p, size_t i, int f) {
  return f ? ((const float*)p)[i] : bf2f(((const u16*)p)[i]);
}

// ---------------------------------------------------------------------------
// Multi-pass split-precision bf16 MFMA GEMM:
//   C[R,NC] = sum_{p<np} Xp[R,K] @ Btp[NC,K]^T  (+bias)
// np = np_base + np_extra * (*dflag)   (wave-uniform runtime pass count)
// EPI: 0 = write bf16 (outb)
//      1 = write f32 (outf)
//      2 = v += res_hi+res_lo, write hi/lo pair (outb/outb2; may alias res, same idx)
//      3 = write bf16 transposed (outb[col*R+row])
//      4 = write hi/lo split pair (outb/outb2)
// 128x128 tile, BK=64, 4 waves, global_load_lds(16B), XOR-swizzled LDS slots.
// ---------------------------------------------------------------------------
template<int EPI>
__global__ __launch_bounds__(256) void gemm_bt(
    const u16* __restrict__ X0, const u16* __restrict__ X1, const u16* __restrict__ X2,
    const u16* __restrict__ Bt0, const u16* __restrict__ Bt1, const u16* __restrict__ Bt2,
    const void* __restrict__ bias, const int* __restrict__ dflag,
    int np_base, int np_extra,
    const u16* res_hi, const u16* res_lo,
    float* outf, u16* outb, u16* outb2,
    int R, int K, int NC)
{
  __shared__ u16 lA[128 * 64];
  __shared__ u16 lB[128 * 64];
  const int tid  = threadIdx.x;
  const int wave = tid >> 6, lane = tid & 63;
  const int quad = lane >> 4, l15 = lane & 15;
  const int wr = wave & 1, wc = wave >> 1;
  const int rblk = blockIdx.x, cblk = blockIdx.y;

  const int np = np_base + (np_extra ? np_extra * (*dflag) : 0);

  const int srow = lane >> 3;
  const int scol = ((lane & 7) ^ (srow & 7)) * 8;

  const u16* Xs[3] = {X0, X1, X2};
  const u16* Bs[3] = {Bt0, Bt1, Bt2};

  f32x4 acc[4][4] = {};

  for (int p = 0; p < np; ++p) {
    const u16* gA = Xs[p] + (size_t)(rblk * 128 + srow) * K + scol;
    const u16* gB = Bs[p] + (size_t)(cblk * 128 + srow) * K + scol;
    for (int k0 = 0; k0 < K; k0 += 64) {
#pragma unroll
      for (int i = 0; i < 4; ++i) {
        const int j = i * 4 + wave;
        __builtin_amdgcn_global_load_lds(
            (const __attribute__((address_space(1))) void*)(gA + (size_t)j * 8 * K + k0),
            (__attribute__((address_space(3))) void*)(lA + j * 512), 16, 0, 0);
        __builtin_amdgcn_global_load_lds(
            (const __attribute__((address_space(1))) void*)(gB + (size_t)j * 8 * K + k0),
            (__attribute__((address_space(3))) void*)(lB + j * 512), 16, 0, 0);
      }
      __syncthreads();
#pragma unroll
      for (int s = 0; s < 2; ++s) {
        bf16x8 af[4], bfr[4];
#pragma unroll
        for (int r = 0; r < 4; ++r) {
          const int row  = wr * 64 + r * 16 + l15;
          const int slot = (s * 4 + quad) ^ (row & 7);
          af[r] = *(const bf16x8*)(lA + row * 64 + slot * 8);
        }
#pragma unroll
        for (int c = 0; c < 4; ++c) {
          const int row  = wc * 64 + c * 16 + l15;
          const int slot = (s * 4 + quad) ^ (row & 7);
          bfr[c] = *(const bf16x8*)(lB + row * 64 + slot * 8);
        }
#pragma unroll
        for (int r = 0; r < 4; ++r)
#pragma unroll
          for (int c = 0; c < 4; ++c)
            acc[r][c] = __builtin_amdgcn_mfma_f32_16x16x32_bf16(af[r], bfr[c], acc[r][c], 0, 0, 0);
      }
      __syncthreads();
    }
  }

  const int fdt = bias ? *dflag : 0;
  const int crow0 = rblk * 128 + wr * 64;
  const int ccol0 = cblk * 128 + wc * 64;
#pragma unroll
  for (int c = 0; c < 4; ++c) {
    const int col = ccol0 + c * 16 + l15;
    const float bcol = bias ? load_in(bias, col, fdt) : 0.0f;
#pragma unroll
    for (int r = 0; r < 4; ++r) {
#pragma unroll
      for (int t = 0; t < 4; ++t) {
        const int row = crow0 + r * 16 + quad * 4 + t;
        const size_t idx = (size_t)row * NC + col;
        float v = acc[r][c][t] + bcol;
        if (EPI == 0) {
          outb[idx] = f2bf(v);
        } else if (EPI == 1) {
          outf[idx] = v;
        } else if (EPI == 2) {
          const float p = bf2f(res_hi[idx]) + bf2f(res_lo[idx]) + v;
          const u16 hi = f2bf(p);
          outb[idx]  = hi;
          outb2[idx] = f2bf(p - bf2f(hi));
        } else if (EPI == 3) {
          outb[(size_t)col * R + row] = f2bf(v);
        } else {  // EPI 4: hi/lo split
          const u16 hi = f2bf(v);
          outb[idx]  = hi;
          outb2[idx] = f2bf(v - bf2f(hi));
        }
      }
    }
  }
}

// ---------------------------------------------------------------------------
// LayerNorm over D=1024 on raw input (dtype via flag); writes hi/lo bf16 pair.
// ---------------------------------------------------------------------------
__global__ __launch_bounds__(256) void ln_row(
    const void* __restrict__ x, const void* __restrict__ g, const void* __restrict__ b,
    const int* __restrict__ dflag, u16* __restrict__ oh, u16* __restrict__ ol)
{
  const int f = *dflag;
  const int row = blockIdx.x, tid = threadIdx.x;
  const int col = tid * 4;
  const size_t base = (size_t)row * 1024 + col;
  float v0, v1, v2, v3;
  if (f) {
    const float4 xv = *(const float4*)((const float*)x + base);
    v0 = xv.x; v1 = xv.y; v2 = xv.z; v3 = xv.w;
  } else {
    const ushort4 xv = *(const ushort4*)((const u16*)x + base);
    v0 = bf2f(xv.x); v1 = bf2f(xv.y); v2 = bf2f(xv.z); v3 = bf2f(xv.w);
  }
  float s  = v0 + v1 + v2 + v3;
  float sq = v0 * v0 + v1 * v1 + v2 * v2 + v3 * v3;
#pragma unroll
  for (int o = 32; o > 0; o >>= 1) { s += __shfl_xor(s, o); sq += __shfl_xor(sq, o); }
  __shared__ float red[8];
  if ((tid & 63) == 0) { red[tid >> 6] = s; red[4 + (tid >> 6)] = sq; }
  __syncthreads();
  s  = red[0] + red[1] + red[2] + red[3];
  sq = red[4] + red[5] + red[6] + red[7];
  const float mean = s * (1.0f / 1024.0f);
  const float var  = sq * (1.0f / 1024.0f) - mean * mean;
  const float rs   = rsqrtf(var + 1e-5f);
  float y[4];
  y[0] = (v0 - mean) * rs * load_in(g, col + 0, f) + load_in(b, col + 0, f);
  y[1] = (v1 - mean) * rs * load_in(g, col + 1, f) + load_in(b, col + 1, f);
  y[2] = (v2 - mean) * rs * load_in(g, col + 2, f) + load_in(b, col + 2, f);
  y[3] = (v3 - mean) * rs * load_in(g, col + 3, f) + load_in(b, col + 3, f);
  ushort4 hv, lv;
  hv.x = f2bf(y[0]); lv.x = f2bf(y[0] - bf2f(hv.x));
  hv.y = f2bf(y[1]); lv.y = f2bf(y[1] - bf2f(hv.y));
  hv.z = f2bf(y[2]); lv.z = f2bf(y[2] - bf2f(hv.z));
  hv.w = f2bf(y[3]); lv.w = f2bf(y[3] - bf2f(hv.w));
  *(ushort4*)(oh + base) = hv;
  *(ushort4*)(ol + base) = lv;
}

// ---------------------------------------------------------------------------
// LN + exact GELU on internal bf16 input; g/b raw dtype.
// MODE 0: write gelu bf16 (ob). MODE 1: p = res_hi+res_lo + gelu, write hi/lo
// pair (oh/ol; may alias res, same-idx read-then-write).
// ---------------------------------------------------------------------------
template<int MODE>
__global__ __launch_bounds__(256) void ln_gelu(
    const u16* __restrict__ x, const void* __restrict__ g, const void* __restrict__ b,
    const int* __restrict__ dflag,
    const u16* res_hi, const u16* res_lo,
    u16* ob, u16* oh, u16* ol)
{
  const int f = *dflag;
  const int row = blockIdx.x, tid = threadIdx.x;
  const int col = tid * 4;
  const size_t base = (size_t)row * 1024 + col;
  const ushort4 xv = *(const ushort4*)(x + base);
  const float v0 = bf2f(xv.x), v1 = bf2f(xv.y), v2 = bf2f(xv.z), v3 = bf2f(xv.w);
  float s  = v0 + v1 + v2 + v3;
  float sq = v0 * v0 + v1 * v1 + v2 * v2 + v3 * v3;
#pragma unroll
  for (int o = 32; o > 0; o >>= 1) { s += __shfl_xor(s, o); sq += __shfl_xor(sq, o); }
  __shared__ float red[8];
  if ((tid & 63) == 0) { red[tid >> 6] = s; red[4 + (tid >> 6)] = sq; }
  __syncthreads();
  s  = red[0] + red[1] + red[2] + red[3];
  sq = red[4] + red[5] + red[6] + red[7];
  const float mean = s * (1.0f / 1024.0f);
  const float var  = sq * (1.0f / 1024.0f) - mean * mean;
  const float rs   = rsqrtf(var + 1e-5f);
  float z[4], h[4];
  z[0] = (v0 - mean) * rs * load_in(g, col + 0, f) + load_in(b, col + 0, f);
  z[1] = (v1 - mean) * rs * load_in(g, col + 1, f) + load_in(b, col + 1, f);
  z[2] = (v2 - mean) * rs * load_in(g, col + 2, f) + load_in(b, col + 2, f);
  z[3] = (v3 - mean) * rs * load_in(g, col + 3, f) + load_in(b, col + 3, f);
#pragma unroll
  for (int i = 0; i < 4; ++i)
    h[i] = 0.5f * z[i] * (1.0f + erff(z[i] * 0.70710678118654752f));
  if (MODE == 0) {
    *(ushort4*)(ob + base) = make_ushort4(f2bf(h[0]), f2bf(h[1]), f2bf(h[2]), f2bf(h[3]));
  } else {
    const ushort4 rh = *(const ushort4*)(res_hi + base);
    const ushort4 rl = *(const ushort4*)(res_lo + base);
    float p[4];
    p[0] = bf2f(rh.x) + bf2f(rl.x) + h[0];
    p[1] = bf2f(rh.y) + bf2f(rl.y) + h[1];
    p[2] = bf2f(rh.z) + bf2f(rl.z) + h[2];
    p[3] = bf2f(rh.w) + bf2f(rl.w) + h[3];
    ushort4 hv, lv;
    hv.x = f2bf(p[0]); lv.x = f2bf(p[0] - bf2f(hv.x));
    hv.y = f2bf(p[1]); lv.y = f2bf(p[1] - bf2f(hv.y));
    hv.z = f2bf(p[2]); lv.z = f2bf(p[2] - bf2f(hv.z));
    hv.w = f2bf(p[3]); lv.w = f2bf(p[3] - bf2f(hv.w));
    *(ushort4*)(oh + base) = hv;
    *(ushort4*)(ol + base) = lv;
  }
}

// ---------------------------------------------------------------------------
// Softmax over M=256; one wave per row, 4 rows per block. f32 in, bf16 out.
// ---------------------------------------------------------------------------
__global__ __launch_bounds__(256) void softmax256(const float* __restrict__ S, u16* __restrict__ A)
{
  const int tid = threadIdx.x, lane = tid & 63, wave = tid >> 6;
  const size_t row = (size_t)blockIdx.x * 4 + wave;
  const float4 v = *(const float4*)(S + row * 256 + lane * 4);
  float m = fmaxf(fmaxf(v.x, v.y), fmaxf(v.z, v.w));
#pragma unroll
  for (int o = 32; o > 0; o >>= 1) m = fmaxf(m, __shfl_xor(m, o));
  const float e0 = expf(v.x - m), e1 = expf(v.y - m), e2 = expf(v.z - m), e3 = expf(v.w - m);
  float s = e0 + e1 + e2 + e3;
#pragma unroll
  for (int o = 32; o > 0; o >>= 1) s += __shfl_xor(s, o);
  const float r = 1.0f / s;
  *(ushort4*)(A + row * 256 + lane * 4) =
      make_ushort4(f2bf(e0 * r), f2bf(e1 * r), f2bf(e2 * r), f2bf(e3 * r));
}

// ---------------------------------------------------------------------------
// Weight transpose->bf16 hi/lo from raw dtype: Wt[n][k] = W[k][n], 5 matrices.
// ---------------------------------------------------------------------------
__global__ __launch_bounds__(256) void wtrans5(
    const void* w0, const void* w1, const void* w2, const void* w3, const void* w4,
    u16* h0, u16* h1, u16* h2, u16* h3, u16* h4,
    u16* l0, u16* l1, u16* l2, u16* l3, u16* l4,
    const int* __restrict__ dflag)
{
  const int f = *dflag;
  const void* W; u16* H; u16* L;
  switch (blockIdx.z) {
    case 0: W = w0; H = h0; L = l0; break;
    case 1: W = w1; H = h1; L = l1; break;
    case 2: W = w2; H = h2; L = l2; break;
    case 3: W = w3; H = h3; L = l3; break;
    default: W = w4; H = h4; L = l4; break;
  }
  __shared__ u16 th[32][33];
  __shared__ u16 tl[32][33];
  const int tx = threadIdx.x & 31, ty = threadIdx.x >> 5;
  const int bx = blockIdx.x, by = blockIdx.y;
#pragma unroll
  for (int i = 0; i < 4; ++i) {
    const int r = ty + i * 8;
    const float v = load_in(W, ((size_t)by * 32 + r) * 1024 + bx * 32 + tx, f);
    const u16 hi = f2bf(v);
    th[r][tx] = hi;
    tl[r][tx] = f2bf(v - bf2f(hi));
  }
  __syncthreads();
#pragma unroll
  for (int i = 0; i < 4; ++i) {
    const int r = ty + i * 8;
    const size_t o = ((size_t)bx * 32 + r) * 1024 + by * 32 + tx;
    H[o] = th[tx][r];
    L[o] = tl[tx][r];
  }
}

__global__ __launch_bounds__(256) void zerof(float* p, int n)
{
  const int i = blockIdx.x * 256 + threadIdx.x;
  if (i < n) p[i] = 0.0f;
}

// ---------------------------------------------------------------------------
// BCIM phase 1: 9-offset Gram band on p2 = hi+lo. grid = (B, 8 d-splits).
// ---------------------------------------------------------------------------
__global__ __launch_bounds__(256) void bcim_dots(
    const u16* __restrict__ p2h, const u16* __restrict__ p2l, float* __restrict__ G)
{
  const int b = blockIdx.x, ds = blockIdx.y;
  __shared__ float T[512][17];
  float acc[9] = {0, 0, 0, 0, 0, 0, 0, 0, 0};
  const int tid = threadIdx.x;
  const int px = tid & 15, py = tid >> 4;
  for (int ch = 0; ch < 8; ++ch) {
    const int d0 = ds * 128 + ch * 16;
#pragma unroll
    for (int i = 0; i < 8; ++i) {
      const int j = i * 256 + tid;
      const int r = j >> 2, q4 = j & 3;
      const size_t base = ((size_t)b * 512 + r) * 1024 + d0 + q4 * 4;
      const ushort4 hv = *(const ushort4*)(p2h + base);
      const ushort4 lv = *(const ushort4*)(p2l + base);
      T[r][q4 * 4 + 0] = bf2f(hv.x) + bf2f(lv.x);
      T[r][q4 * 4 + 1] = bf2f(hv.y) + bf2f(lv.y);
      T[r][q4 * 4 + 2] = bf2f(hv.z) + bf2f(lv.z);
      T[r][q4 * 4 + 3] = bf2f(hv.w) + bf2f(lv.w);
    }
    __syncthreads();
    float a0[16], a1[16];
#pragma unroll
    for (int dc = 0; dc < 16; ++dc) { a0[dc] = T[tid][dc]; a1[dc] = T[tid + 256][dc]; }
#pragma unroll
    for (int o = 0; o < 9; ++o) {
      const int dy = o / 3 - 1, dx = o % 3 - 1;
      const int qx = px + dx, qy = py + dy;
      if (qx >= 0 && qx < 16 && qy >= 0 && qy < 16) {
        const int qp = qy * 16 + qx;
        float sum = 0.0f;
#pragma unroll
        for (int dc = 0; dc < 16; ++dc)
          sum += a0[dc] * T[qp][dc] + a1[dc] * T[qp + 256][dc];
        acc[o] += sum;
      }
    }
    __syncthreads();
  }
#pragma unroll
  for (int o = 0; o < 9; ++o)
    atomicAdd(&G[((size_t)b * 9 + o) * 256 + tid], acc[o]);
}

// BCIM phase 2: sim[b][pix]
__global__ __launch_bounds__(256) void bcim_sim_k(const float* __restrict__ G, float* __restrict__ sim)
{
  const int b = blockIdx.x, tid = threadIdx.x;
  __shared__ float nrm[256];
  const float nv = sqrtf(G[((size_t)b * 9 + 4) * 256 + tid]);
  nrm[tid] = nv;
  __syncthreads();
  const int px = tid & 15, py = tid >> 4;
  float s = 0.0f;
#pragma unroll
  for (int o = 0; o < 9; ++o) {
    const int dy = o / 3 - 1, dx = o % 3 - 1;
    const int qx = px + dx, qy = py + dy;
    if (qx >= 0 && qx < 16 && qy >= 0 && qy < 16)
      s += G[((size_t)b * 9 + o) * 256 + tid] / (nv * nrm[qy * 16 + qx]);
  }
  sim[b * 256 + tid] = s * (1.0f / 9.0f);
}

// BCIM phase 3: out[b,n,d] = (p2h+p2l)[b,n,d] * sim[b][n&255]  (f32 out)
__global__ __launch_bounds__(256) void bcim_scale(
    const u16* __restrict__ p2h, const u16* __restrict__ p2l,
    const float* __restrict__ sim, float* __restrict__ out)
{
  const size_t i4 = (size_t)blockIdx.x * 256 + threadIdx.x;
  const size_t base = i4 * 4;
  const ushort4 hv = *(const ushort4*)(p2h + base);
  const ushort4 lv = *(const ushort4*)(p2l + base);
  const size_t n = base >> 10;
  const size_t b = n >> 9;
  const int pix = (int)(n & 255);
  const float s = sim[b * 256 + pix];
  *(float4*)(out + base) = make_float4(
      (bf2f(hv.x) + bf2f(lv.x)) * s, (bf2f(hv.y) + bf2f(lv.y)) * s,
      (bf2f(hv.z) + bf2f(lv.z)) * s, (bf2f(hv.w) + bf2f(lv.w)) * s);
}

// ---------------------------------------------------------------------------
extern "C" void kernel_launch(void* const* d_in, const int* in_sizes, int n_in,
                              void* d_out, int out_size, void* d_ws, size_t ws_size,
                              hipStream_t stream)
{
  (void)in_sizes; (void)n_in; (void)out_size; (void)ws_size;
  const void* p_vector      = d_in[0];
  const void* object_vector = d_in[1];
  const void* ln_p_g = d_in[2];
  const void* ln_p_b = d_in[3];
  const void* ln_o_g = d_in[4];
  const void* ln_o_b = d_in[5];
  const void* Wq = d_in[6];  const void* bq = d_in[7];
  const void* Wk = d_in[8];  const void* bk = d_in[9];
  const void* Wv = d_in[10]; const void* bv = d_in[11];
  const void* W1 = d_in[12]; const void* b1 = d_in[13];
  const void* ln1_g = d_in[14]; const void* ln1_b = d_in[15];
  const void* W2 = d_in[16]; const void* b2 = d_in[17];
  const void* ln2_g = d_in[18]; const void* ln2_b = d_in[19];
  float* out = (float*)d_out;

  char* ws = (char*)d_ws;
  size_t off = 0;
  auto alloc = [&](size_t bytes) -> void* {
    void* p = ws + off;
    off += (bytes + 255) & ~(size_t)255;
    return p;
  };
  int* dflag = (int*)alloc(256);
  u16* WqH = (u16*)alloc((size_t)D_DIM * D_DIM * 2);
  u16* WkH = (u16*)alloc((size_t)D_DIM * D_DIM * 2);
  u16* WvH = (u16*)alloc((size_t)D_DIM * D_DIM * 2);
  u16* W1H = (u16*)alloc((size_t)D_DIM * D_DIM * 2);
  u16* W2H = (u16*)alloc((size_t)D_DIM * D_DIM * 2);
  u16* WqL = (u16*)alloc((size_t)D_DIM * D_DIM * 2);
  u16* WkL = (u16*)alloc((size_t)D_DIM * D_DIM * 2);
  u16* WvL = (u16*)alloc((size_t)D_DIM * D_DIM * 2);
  u16* W1L = (u16*)alloc((size_t)D_DIM * D_DIM * 2);
  u16* W2L = (u16*)alloc((size_t)D_DIM * D_DIM * 2);
  u16* PH = (u16*)alloc((size_t)BN * D_DIM * 2);   // pn_hi -> p1_hi -> p2_hi
  u16* PL = (u16*)alloc((size_t)BN * D_DIM * 2);   // pn_lo -> p1_lo -> p2_lo
  u16* QH = (u16*)alloc((size_t)BN * D_DIM * 2);   // q_hi -> y1 -> y2
  u16* QL = (u16*)alloc((size_t)BN * D_DIM * 2);   // q_lo -> h1
  float* S_f = (float*)alloc((size_t)BN * M_DIM * 4);
  u16* A_b   = (u16*)alloc((size_t)BN * M_DIM * 2);
  u16* onH = (u16*)alloc((size_t)M_DIM * D_DIM * 2);
  u16* onL = (u16*)alloc((size_t)M_DIM * D_DIM * 2);
  u16* kH  = (u16*)alloc((size_t)M_DIM * D_DIM * 2);
  u16* kL  = (u16*)alloc((size_t)M_DIM * D_DIM * 2);
  u16* vT  = (u16*)alloc((size_t)D_DIM * M_DIM * 2);
  float* G   = (float*)alloc((size_t)B_IMG * 9 * 256 * 4);
  float* sim = (float*)alloc((size_t)B_IMG * 256 * 4);

  // 0. dtype detect, weight transposes (hi/lo), zero G
  detect_dtype<<<1, 64, 0, stream>>>((const u16*)p_vector, dflag);
  wtrans5<<<dim3(32, 32, 5), 256, 0, stream>>>(Wq, Wk, Wv, W1, W2,
      WqH, WkH, WvH, W1H, W2H, WqL, WkL, WvL, W1L, W2L, dflag);
  zerof<<<(B_IMG * 9 * 256 + 255) / 256, 256, 0, stream>>>(G, B_IMG * 9 * 256);

  // 1. LayerNorms -> hi/lo pairs
  ln_row<<<BN, 256, 0, stream>>>(p_vector, ln_p_g, ln_p_b, dflag, PH, PL);
  ln_row<<<M_DIM, 256, 0, stream>>>(object_vector, ln_o_g, ln_o_b, dflag, onH, onL);

  // 2. k (hi/lo), v^T, q (hi/lo) — split passes; W_lo pass only when inputs f32
  gemm_bt<4><<<dim3(2, 8), 256, 0, stream>>>(onH, onL, onH, WkH, WkH, WkL,
      bk, dflag, 2, 1, nullptr, nullptr, nullptr, kH, kL, M_DIM, D_DIM, D_DIM);
  gemm_bt<3><<<dim3(2, 8), 256, 0, stream>>>(onH, onL, onH, WvH, WvH, WvL,
      bv, dflag, 2, 1, nullptr, nullptr, nullptr, vT, nullptr, M_DIM, D_DIM, D_DIM);
  gemm_bt<4><<<dim3(256, 8), 256, 0, stream>>>(PH, PL, PH, WqH, WqH, WqL,
      bq, dflag, 2, 1, nullptr, nullptr, nullptr, QH, QL, BN, D_DIM, D_DIM);

  // 3. S = (q_hi+q_lo)(k_hi+k_lo)^T (3 split passes); softmax -> A bf16
  gemm_bt<1><<<dim3(256, 2), 256, 0, stream>>>(QH, QL, QH, kH, kH, kL,
      nullptr, dflag, 3, 0, nullptr, nullptr, S_f, nullptr, nullptr, BN, D_DIM, M_DIM);
  softmax256<<<BN / 4, 256, 0, stream>>>(S_f, A_b);

  // 4. p1 = pn + A v  (in-place hi/lo over PH/PL)
  gemm_bt<2><<<dim3(256, 8), 256, 0, stream>>>(A_b, nullptr, nullptr, vT, nullptr, nullptr,
      nullptr, dflag, 1, 0, PH, PL, nullptr, PH, PL, BN, M_DIM, D_DIM);

  // 5. y1 = p1_hi W1 + b1 -> QH ; h1 = gelu(LN(y1)) -> QL
  gemm_bt<0><<<dim3(256, 8), 256, 0, stream>>>(PH, nullptr, nullptr, W1H, nullptr, nullptr,
      b1, dflag, 1, 0, nullptr, nullptr, nullptr, QH, nullptr, BN, D_DIM, D_DIM);
  ln_gelu<0><<<BN, 256, 0, stream>>>(QH, ln1_g, ln1_b, dflag, nullptr, nullptr, QL, nullptr, nullptr);

  // 6. y2 = h1 W2 + b2 -> QH ; p2 = p1 + gelu(LN(y2)) (in-place hi/lo over PH/PL)
  gemm_bt<0><<<dim3(256, 8), 256, 0, stream>>>(QL, nullptr, nullptr, W2H, nullptr, nullptr,
      b2, dflag, 1, 0, nullptr, nullptr, nullptr, QH, nullptr, BN, D_DIM, D_DIM);
  ln_gelu<1><<<BN, 256, 0, stream>>>(QH, ln2_g, ln2_b, dflag, PH, PL, nullptr, PH, PL);

  // 7. BCIM
  bcim_dots<<<dim3(B_IMG, 8), 256, 0, stream>>>(PH, PL, G);
  bcim_sim_k<<<B_IMG, 256, 0, stream>>>(G, sim);
  bcim_scale<<<(BN * D_DIM / 4) / 256, 256, 0, stream>>>(PH, PL, sim, out);
}